// Round 6
// baseline (331.699 us; speedup 1.0000x reference)
//
#include <hip/hip_runtime.h>

// GMMNet: B=4,S=8,C=3,H=W=384,K=5. Pointwise per pixel; scan over S carries
// per-pixel state (pi[5], mu[15], rinv[5]=1/sigma) in registers.
//
// Round 6: 4 pixels/thread as TWO packed float2 chains. Round 5 showed the
// LDS pipe is the co-bottleneck: ~220 merged ds_read issues per wave-step
// re-reading the 871 staged weights (anti-LICM keeps them unhoisted), ~8-12
// cyc each ~= 55-85% of total cycles on the LDS pipe. Weight traffic is
// per-WAVE-step, so 4 px/thread halves LDS instrs per pixel; each ds_read
// now feeds two v_pk_fma_f32. 64-thread blocks (2304 blocks = 9 waves/CU)
// for even scheduler packing. Opaque-woff anti-LICM retained.

namespace {

constexpr int Kk = 5;
constexpr int Cc = 3;
constexpr int CKc = 15;   // C*K
constexpr int Bb = 4;
constexpr int Ss = 8;
constexpr int HWc = 384 * 384;
constexpr int HW4 = HWc / 4;          // pixel-quads per image (36864)
constexpr int BLOCK = 64;

typedef float v2f __attribute__((ext_vector_type(2)));
typedef float v4f __attribute__((ext_vector_type(4)));

// LDS layout (float offsets); bases/pitches %4==0.
constexpr int PW1 = 0,   PP1 = 12;  // pi_w1  5x10
constexpr int PB1 = 60;             // pi_b1  5 (pad 8)
constexpr int PW2 = 68,  PP2 = 8;   // pi_w2  5x5
constexpr int PB2 = 108;            // pi_b2  5 (pad 8)
constexpr int MW1 = 116, MP1 = 24;  // mu_w1  15x23
constexpr int MB1 = 476;            // mu_b1  15 (pad 16)
constexpr int MW2 = 492, MP2 = 16;  // mu_w2  15x15
constexpr int MB2 = 732;            // mu_b2  15 (pad 16)
constexpr int SW1 = 748, SP1 = 24;  // sg_w1  5x23
constexpr int SB1 = 868;            // sg_b1  5 (pad 8)
constexpr int SW2 = 876, SP2 = 8;   // sg_w2  5x5
constexpr int SB2 = 916;            // sg_b2  5 (pad 8)
constexpr int GW1 = 924, GP1 = 8;   // ga_w1  5x5
constexpr int GB1 = 964;            // ga_b1  5 (pad 8)
constexpr int GW2 = 972;            // ga_w2  5 (pad 8)
constexpr int GB2 = 980;            // ga_b2  1 (pad 4)
constexpr int WTOT = 984;           // 3936 B

__device__ __forceinline__ float rcpf(float x) { return __builtin_amdgcn_rcpf(x); }
__device__ __forceinline__ float ex2(float x) { return __builtin_amdgcn_exp2f(x); }

__device__ __forceinline__ v2f vsplat(float w) { v2f r = {w, w}; return r; }
__device__ __forceinline__ v2f vfma(v2f a, v2f b, v2f c) { return __builtin_elementwise_fma(a, b, c); }
__device__ __forceinline__ v2f wfma(float w, v2f x, v2f c) { return vfma(vsplat(w), x, c); }
__device__ __forceinline__ v2f vexp2(v2f v) { v2f r; r.x = ex2(v.x); r.y = ex2(v.y); return r; }
__device__ __forceinline__ v2f vrcp(v2f v) { v2f r; r.x = rcpf(v.x); r.y = rcpf(v.y); return r; }
__device__ __forceinline__ v2f vmax(v2f a, v2f b) { return __builtin_elementwise_max(a, b); }
__device__ __forceinline__ v2f vrelu(v2f a) { return vmax(a, vsplat(0.0f)); }
constexpr float LOG2E = 1.4426950408889634f;
__device__ __forceinline__ v2f vsigm(v2f a) { return vrcp(vsplat(1.0f) + vexp2(vsplat(-LOG2E) * a)); }

__device__ __forceinline__ void stage(float* W, int dst, const float* __restrict__ src,
                                      int rows, int cols, int pitch, int tid) {
    for (int t = tid; t < rows * pitch; t += BLOCK) {
        int r = t / pitch, c = t - r * pitch;
        W[dst + t] = (c < cols) ? src[r * cols + c] : 0.0f;
    }
}

__global__ __launch_bounds__(BLOCK) void gmm_seq_kernel(
    const float* __restrict__ frames,
    const float* __restrict__ mu0,
    const float* __restrict__ pw1, const float* __restrict__ pb1,
    const float* __restrict__ pw2, const float* __restrict__ pb2,
    const float* __restrict__ mw1, const float* __restrict__ mb1,
    const float* __restrict__ mw2, const float* __restrict__ mb2,
    const float* __restrict__ sw1, const float* __restrict__ sb1,
    const float* __restrict__ sw2, const float* __restrict__ sb2,
    const float* __restrict__ gw1, const float* __restrict__ gb1,
    const float* __restrict__ gw2, const float* __restrict__ gb2,
    float* __restrict__ out)
{
    __shared__ float sW[WTOT];
    {
        const int t = threadIdx.x;
        stage(sW, PW1, pw1, Kk, 2 * Kk, PP1, t);
        stage(sW, PB1, pb1, 1, Kk, 8, t);
        stage(sW, PW2, pw2, Kk, Kk, PP2, t);
        stage(sW, PB2, pb2, 1, Kk, 8, t);
        stage(sW, MW1, mw1, CKc, 23, MP1, t);
        stage(sW, MB1, mb1, 1, CKc, 16, t);
        stage(sW, MW2, mw2, CKc, CKc, MP2, t);
        stage(sW, MB2, mb2, 1, CKc, 16, t);
        stage(sW, SW1, sw1, Kk, 23, SP1, t);
        stage(sW, SB1, sb1, 1, Kk, 8, t);
        stage(sW, SW2, sw2, Kk, Kk, SP2, t);
        stage(sW, SB2, sb2, 1, Kk, 8, t);
        stage(sW, GW1, gw1, Kk, Kk, GP1, t);
        stage(sW, GB1, gb1, 1, Kk, 8, t);
        stage(sW, GW2, gw2, 1, Kk, 8, t);
        stage(sW, GB2, gb2, 1, 1, 4, t);
    }
    __syncthreads();

    const int t4 = blockIdx.x * BLOCK + threadIdx.x;   // one thread = 4 adjacent px
    const int b   = t4 / HW4;
    const int rem = t4 - b * HW4;

    const float C0 = 0.06349363593424097f;      // (2*pi)^{-3/2}
    const float NH_L2E = -0.7213475204444817f;  // -0.5 * log2(e)

    // Per-quad carried state: two packed pairs p=0,1.
    v2f pi[2][Kk], mu[2][CKc], rinv[2][Kk];     // rinv = 1/sigma
#pragma unroll
    for (int p = 0; p < 2; p++)
#pragma unroll
        for (int k = 0; k < Kk; k++) { pi[p][k] = vsplat(0.2f); rinv[p][k] = vsplat(1.0f); }
    {
        const float* mp = mu0 + (size_t)b * CKc * HWc;
#pragma unroll
        for (int j = 0; j < CKc; j++) {
            v4f m4 = reinterpret_cast<const v4f*>(mp + (size_t)j * HWc)[rem];
            mu[0][j] = v2f{m4.x, m4.y};
            mu[1][j] = v2f{m4.z, m4.w};
        }
    }

    const float* fbase = frames + ((size_t)b * Ss * Cc) * HWc;
    v2f x[2][Cc];
#pragma unroll
    for (int c = 0; c < Cc; c++) {
        v4f f4 = reinterpret_cast<const v4f*>(fbase + (size_t)c * HWc)[rem];
        x[0][c] = v2f{f4.x, f4.y};
        x[1][c] = v2f{f4.z, f4.w};
    }

#pragma unroll 1
    for (int s = 0; s < Ss; s++) {
        // Opaque per-iteration LDS offset: prevents machine-LICM from hoisting
        // the ~871 weight reads into whole-loop-live registers.
        unsigned woff = 0;
        asm volatile("" : "+v"(woff));
        woff &= ~3u;
#define LW(IDX) sW[woff + (IDX)]

        // Prefetch next frame's pixels.
        v2f xn[2][Cc];
        if (s + 1 < Ss) {
            const float* fp = fbase + ((size_t)(s + 1) * Cc) * HWc;
#pragma unroll
            for (int c = 0; c < Cc; c++) {
                v4f f4 = reinterpret_cast<const v4f*>(fp + (size_t)c * HWc)[rem];
                xn[0][c] = v2f{f4.x, f4.y};
                xn[1][c] = v2f{f4.z, f4.w};
            }
        }

        // ---- density(x; mu, 1/rinv) ----
        v2f alpha[2][Kk], rho[2][Kk];
#pragma unroll
        for (int k = 0; k < Kk; k++)
#pragma unroll
            for (int p = 0; p < 2; p++) {
                v2f inv_s2 = rinv[p][k] * rinv[p][k];
                v2f d0 = x[p][0] - mu[p][k * Cc + 0];
                v2f d1 = x[p][1] - mu[p][k * Cc + 1];
                v2f d2 = x[p][2] - mu[p][k * Cc + 2];
                v2f dist = vfma(d0, d0, vfma(d1, d1, d2 * d2));
                v2f coef = vsplat(C0) * inv_s2 * rinv[p][k];   // C0 * rinv^3
                v2f dens = coef * vexp2(vsplat(NH_L2E) * dist * inv_s2);
                alpha[p][k] = pi[p][k] * dens;
                rho[p][k] = alpha[p][k] * dens;
            }

        // ---- pi MLP (10 -> 5 -> 5) + softmax over K ----
        v2f piN[2][Kk];
        {
            v2f h[2][Kk];
#pragma unroll
            for (int j = 0; j < Kk; j++) {
                float bw = LW(PB1 + j);
                v2f a0 = vsplat(bw), a1 = vsplat(bw);
#pragma unroll
                for (int i = 0; i < Kk; i++) {
                    float w = LW(PW1 + j * PP1 + i);
                    a0 = wfma(w, pi[0][i], a0); a1 = wfma(w, pi[1][i], a1);
                }
#pragma unroll
                for (int i = 0; i < Kk; i++) {
                    float w = LW(PW1 + j * PP1 + Kk + i);
                    a0 = wfma(w, alpha[0][i], a0); a1 = wfma(w, alpha[1][i], a1);
                }
                h[0][j] = vrelu(a0); h[1][j] = vrelu(a1);
            }
            v2f o[2][Kk];
            v2f m0 = vsplat(-1e30f), m1 = vsplat(-1e30f);
#pragma unroll
            for (int j = 0; j < Kk; j++) {
                float bw = LW(PB2 + j);
                v2f a0 = vsplat(bw), a1 = vsplat(bw);
#pragma unroll
                for (int i = 0; i < Kk; i++) {
                    float w = LW(PW2 + j * PP2 + i);
                    a0 = wfma(w, h[0][i], a0); a1 = wfma(w, h[1][i], a1);
                }
                o[0][j] = a0; m0 = vmax(m0, a0);
                o[1][j] = a1; m1 = vmax(m1, a1);
            }
            v2f s0 = vsplat(0.0f), s1 = vsplat(0.0f);
#pragma unroll
            for (int j = 0; j < Kk; j++) {
                o[0][j] = vexp2(vsplat(LOG2E) * (o[0][j] - m0)); s0 = s0 + o[0][j];
                o[1][j] = vexp2(vsplat(LOG2E) * (o[1][j] - m1)); s1 = s1 + o[1][j];
            }
            v2f r0 = vrcp(s0), r1 = vrcp(s1);
#pragma unroll
            for (int j = 0; j < Kk; j++) { piN[0][j] = o[0][j] * r0; piN[1][j] = o[1][j] * r1; }
        }

        // ---- mu MLP (23 -> 15 -> 15), sigmoid ----
        v2f muN[2][CKc];
        {
            v2f h[2][CKc];
#pragma unroll
            for (int j = 0; j < CKc; j++) {
                float bw = LW(MB1 + j);
                v2f a0 = vsplat(bw), a1 = vsplat(bw);
#pragma unroll
                for (int i = 0; i < Cc; i++) {
                    float w = LW(MW1 + j * MP1 + i);
                    a0 = wfma(w, x[0][i], a0); a1 = wfma(w, x[1][i], a1);
                }
#pragma unroll
                for (int i = 0; i < CKc; i++) {
                    float w = LW(MW1 + j * MP1 + 3 + i);
                    a0 = wfma(w, mu[0][i], a0); a1 = wfma(w, mu[1][i], a1);
                }
#pragma unroll
                for (int i = 0; i < Kk; i++) {
                    float w = LW(MW1 + j * MP1 + 18 + i);
                    a0 = wfma(w, rho[0][i], a0); a1 = wfma(w, rho[1][i], a1);
                }
                h[0][j] = vrelu(a0); h[1][j] = vrelu(a1);
            }
#pragma unroll
            for (int j = 0; j < CKc; j++) {
                float bw = LW(MB2 + j);
                v2f a0 = vsplat(bw), a1 = vsplat(bw);
#pragma unroll
                for (int i = 0; i < CKc; i++) {
                    float w = LW(MW2 + j * MP2 + i);
                    a0 = wfma(w, h[0][i], a0); a1 = wfma(w, h[1][i], a1);
                }
                muN[0][j] = vsigm(a0); muN[1][j] = vsigm(a1);
            }
        }

        // ---- sigma MLP (23 -> 5 -> 5): rinvN = exp(-relu(a)) = 1/sigma_new ----
        v2f rinvN[2][Kk];
        {
            v2f h[2][Kk];
#pragma unroll
            for (int j = 0; j < Kk; j++) {
                float bw = LW(SB1 + j);
                v2f a0 = vsplat(bw), a1 = vsplat(bw);
#pragma unroll
                for (int i = 0; i < Cc; i++) {
                    float w = LW(SW1 + j * SP1 + i);
                    a0 = wfma(w, x[0][i], a0); a1 = wfma(w, x[1][i], a1);
                }
#pragma unroll
                for (int i = 0; i < CKc; i++) {
                    float w = LW(SW1 + j * SP1 + 3 + i);
                    a0 = wfma(w, muN[0][i], a0); a1 = wfma(w, muN[1][i], a1);
                }
#pragma unroll
                for (int i = 0; i < Kk; i++) {
                    float w = LW(SW1 + j * SP1 + 18 + i);
                    a0 = wfma(w, rho[0][i], a0); a1 = wfma(w, rho[1][i], a1);
                }
                h[0][j] = vrelu(a0); h[1][j] = vrelu(a1);
            }
#pragma unroll
            for (int j = 0; j < Kk; j++) {
                float bw = LW(SB2 + j);
                v2f a0 = vsplat(bw), a1 = vsplat(bw);
#pragma unroll
                for (int i = 0; i < Kk; i++) {
                    float w = LW(SW2 + j * SP2 + i);
                    a0 = wfma(w, h[0][i], a0); a1 = wfma(w, h[1][i], a1);
                }
                rinvN[0][j] = vexp2(vsplat(-LOG2E) * vrelu(a0));
                rinvN[1][j] = vexp2(vsplat(-LOG2E) * vrelu(a1));
            }
        }

        // ---- dens2(x; muN, 1/rinvN), gamma MLP (5 -> 5 -> 1), sigmoid ----
        v2f gin[2][Kk];
#pragma unroll
        for (int k = 0; k < Kk; k++)
#pragma unroll
            for (int p = 0; p < 2; p++) {
                v2f inv_s2 = rinvN[p][k] * rinvN[p][k];
                v2f d0 = x[p][0] - muN[p][k * Cc + 0];
                v2f d1 = x[p][1] - muN[p][k * Cc + 1];
                v2f d2 = x[p][2] - muN[p][k * Cc + 2];
                v2f dist = vfma(d0, d0, vfma(d1, d1, d2 * d2));
                v2f coef = vsplat(C0) * inv_s2 * rinvN[p][k];
                gin[p][k] = piN[p][k] * (coef * vexp2(vsplat(NH_L2E) * dist * inv_s2));
            }
        {
            v2f h[2][Kk];
#pragma unroll
            for (int j = 0; j < Kk; j++) {
                float bw = LW(GB1 + j);
                v2f a0 = vsplat(bw), a1 = vsplat(bw);
#pragma unroll
                for (int i = 0; i < Kk; i++) {
                    float w = LW(GW1 + j * GP1 + i);
                    a0 = wfma(w, gin[0][i], a0); a1 = wfma(w, gin[1][i], a1);
                }
                h[0][j] = vrelu(a0); h[1][j] = vrelu(a1);
            }
            float bw = LW(GB2);
            v2f g0 = vsplat(bw), g1 = vsplat(bw);
#pragma unroll
            for (int i = 0; i < Kk; i++) {
                float w = LW(GW2 + i);
                g0 = wfma(w, h[0][i], g0); g1 = wfma(w, h[1][i], g1);
            }
            g0 = vsigm(g0); g1 = vsigm(g1);
            v4f o4 = {g0.x, g0.y, g1.x, g1.y};
            reinterpret_cast<v4f*>(out + (size_t)(b * Ss + s) * HWc)[rem] = o4;
        }
#undef LW

        // ---- carry state ----
#pragma unroll
        for (int p = 0; p < 2; p++) {
#pragma unroll
            for (int k = 0; k < Kk; k++) { pi[p][k] = piN[p][k]; rinv[p][k] = rinvN[p][k]; }
#pragma unroll
            for (int j = 0; j < CKc; j++) mu[p][j] = muN[p][j];
#pragma unroll
            for (int c = 0; c < Cc; c++) x[p][c] = xn[p][c];
        }
    }
}

} // namespace

extern "C" void kernel_launch(void* const* d_in, const int* in_sizes, int n_in,
                              void* d_out, int out_size, void* d_ws, size_t ws_size,
                              hipStream_t stream) {
    const float* frames = (const float*)d_in[0];
    const float* mu0    = (const float*)d_in[2];
    const float* pw1 = (const float*)d_in[3];
    const float* pb1 = (const float*)d_in[4];
    const float* pw2 = (const float*)d_in[5];
    const float* pb2 = (const float*)d_in[6];
    const float* mw1 = (const float*)d_in[7];
    const float* mb1 = (const float*)d_in[8];
    const float* mw2 = (const float*)d_in[9];
    const float* mb2 = (const float*)d_in[10];
    const float* sw1 = (const float*)d_in[11];
    const float* sb1 = (const float*)d_in[12];
    const float* sw2 = (const float*)d_in[13];
    const float* sb2 = (const float*)d_in[14];
    const float* gw1 = (const float*)d_in[15];
    const float* gb1 = (const float*)d_in[16];
    const float* gw2 = (const float*)d_in[17];
    const float* gb2 = (const float*)d_in[18];
    float* out = (float*)d_out;

    const int total4 = Bb * HW4;         // 147,456 pixel-quads
    const int grid = (total4 + BLOCK - 1) / BLOCK;   // 2304 blocks (1 wave each)

    gmm_seq_kernel<<<grid, BLOCK, 0, stream>>>(
        frames, mu0,
        pw1, pb1, pw2, pb2,
        mw1, mb1, mw2, mb2,
        sw1, sb1, sw2, sb2,
        gw1, gb1, gw2, gb2,
        out);
}

// Round 7
// 283.783 us; speedup vs baseline: 1.1688x; 1.1688x over previous
//
#include <hip/hip_runtime.h>

// GMMNet: B=4,S=8,C=3,H=W=384,K=5. Pointwise per pixel; scan over S carries
// per-pixel state (pi[5], mu[15], rinv[5]=1/sigma) in registers.
//
// Round 7: weights via the SCALAR path (SMEM/s_load + constant cache), no LDS.
// Weights are wave-uniform: reading them through uniform pointers with
// compile-time indices makes every weight an SGPR operand of v_pk_fma_f32 —
// no LDS broadcast traffic, no VGPR weight copies. The 3.5 KB weight set is
// scalar-cache resident after the first step. An opaque per-iteration SCALAR
// offset ("+s" asm) keeps addresses uniform (s_load preserved) while blocking
// cross-step hoisting (round 2: hoist -> 188 VGPR; round 3: cap -> spill).
// 2px/thread packed float2 math retained (R5 = best so far, 184.5 us);
// 4608 waves in 2304 blocks of 128 -> 9 blocks/CU, even distribution.

namespace {

constexpr int Kk = 5;
constexpr int Cc = 3;
constexpr int CKc = 15;   // C*K
constexpr int Bb = 4;
constexpr int Ss = 8;
constexpr int HWc = 384 * 384;
constexpr int HW2 = HWc / 2;          // pixel-pairs per image
constexpr int BLOCK = 128;

typedef float v2f __attribute__((ext_vector_type(2)));

__device__ __forceinline__ float rcpf(float x) { return __builtin_amdgcn_rcpf(x); }
__device__ __forceinline__ float ex2(float x) { return __builtin_amdgcn_exp2f(x); }

__device__ __forceinline__ v2f vsplat(float w) { v2f r = {w, w}; return r; }
__device__ __forceinline__ v2f vfma(v2f a, v2f b, v2f c) { return __builtin_elementwise_fma(a, b, c); }
__device__ __forceinline__ v2f wfma(float w, v2f x, v2f c) { return vfma(vsplat(w), x, c); }
__device__ __forceinline__ v2f vexp2(v2f v) { v2f r; r.x = ex2(v.x); r.y = ex2(v.y); return r; }
__device__ __forceinline__ v2f vrcp(v2f v) { v2f r; r.x = rcpf(v.x); r.y = rcpf(v.y); return r; }
__device__ __forceinline__ v2f vmax(v2f a, v2f b) { return __builtin_elementwise_max(a, b); }
__device__ __forceinline__ v2f vrelu(v2f a) { return vmax(a, vsplat(0.0f)); }
constexpr float LOG2E = 1.4426950408889634f;
__device__ __forceinline__ v2f vsigm(v2f a) { return vrcp(vsplat(1.0f) + vexp2(vsplat(-LOG2E) * a)); }

__global__ __launch_bounds__(BLOCK) void gmm_seq_kernel(
    const float* __restrict__ frames,
    const float* __restrict__ mu0,
    const float* __restrict__ pw1, const float* __restrict__ pb1,
    const float* __restrict__ pw2, const float* __restrict__ pb2,
    const float* __restrict__ mw1, const float* __restrict__ mb1,
    const float* __restrict__ mw2, const float* __restrict__ mb2,
    const float* __restrict__ sw1, const float* __restrict__ sb1,
    const float* __restrict__ sw2, const float* __restrict__ sb2,
    const float* __restrict__ gw1, const float* __restrict__ gb1,
    const float* __restrict__ gw2, const float* __restrict__ gb2,
    float* __restrict__ out)
{
    const int t2 = blockIdx.x * BLOCK + threadIdx.x;   // one thread = 2 adjacent px
    const int b   = t2 / HW2;
    const int rem = t2 - b * HW2;

    const float C0 = 0.06349363593424097f;      // (2*pi)^{-3/2}
    const float NH_L2E = -0.7213475204444817f;  // -0.5 * log2(e)

    // Per-pixel-pair carried state.
    v2f pi[Kk], mu[CKc], rinv[Kk];              // rinv = 1/sigma
#pragma unroll
    for (int k = 0; k < Kk; k++) { pi[k] = vsplat(0.2f); rinv[k] = vsplat(1.0f); }
    {
        const float* mp = mu0 + (size_t)b * CKc * HWc;
#pragma unroll
        for (int j = 0; j < CKc; j++)
            mu[j] = reinterpret_cast<const v2f*>(mp + (size_t)j * HWc)[rem];
    }

    const float* fbase = frames + ((size_t)b * Ss * Cc) * HWc;
    v2f x[Cc];
#pragma unroll
    for (int c = 0; c < Cc; c++)
        x[c] = reinterpret_cast<const v2f*>(fbase + (size_t)c * HWc)[rem];

#pragma unroll 1
    for (int s = 0; s < Ss; s++) {
        // Opaque per-iteration SCALAR offset: value is always 0 but the
        // compiler can't prove it. Addresses stay wave-uniform (-> s_load
        // path preserved), but weight loads are loop-variant -> no cross-step
        // hoisting into whole-loop-live registers.
        long woff = 0;
        asm volatile("" : "+s"(woff));
#define W(P, IDX) (P)[woff + (IDX)]

        // Prefetch next frame's pixels.
        v2f xn[Cc];
        if (s + 1 < Ss) {
            const float* fp = fbase + ((size_t)(s + 1) * Cc) * HWc;
#pragma unroll
            for (int c = 0; c < Cc; c++)
                xn[c] = reinterpret_cast<const v2f*>(fp + (size_t)c * HWc)[rem];
        }

        // ---- density(x; mu, 1/rinv) ----
        v2f alpha[Kk], rho[Kk];
#pragma unroll
        for (int k = 0; k < Kk; k++) {
            v2f inv_s2 = rinv[k] * rinv[k];
            v2f d0 = x[0] - mu[k * Cc + 0];
            v2f d1 = x[1] - mu[k * Cc + 1];
            v2f d2 = x[2] - mu[k * Cc + 2];
            v2f dist = vfma(d0, d0, vfma(d1, d1, d2 * d2));
            v2f coef = vsplat(C0) * inv_s2 * rinv[k];      // C0 * rinv^3
            v2f dens = coef * vexp2(vsplat(NH_L2E) * dist * inv_s2);
            alpha[k] = pi[k] * dens;
            rho[k] = alpha[k] * dens;
        }

        // ---- pi MLP (10 -> 5 -> 5) + softmax over K ----
        v2f piN[Kk];
        {
            v2f h[Kk];
#pragma unroll
            for (int j = 0; j < Kk; j++) {
                v2f a = vsplat(W(pb1, j));
#pragma unroll
                for (int i = 0; i < Kk; i++) a = wfma(W(pw1, j * 2 * Kk + i), pi[i], a);
#pragma unroll
                for (int i = 0; i < Kk; i++) a = wfma(W(pw1, j * 2 * Kk + Kk + i), alpha[i], a);
                h[j] = vrelu(a);
            }
            v2f o[Kk];
            v2f m = vsplat(-1e30f);
#pragma unroll
            for (int j = 0; j < Kk; j++) {
                v2f a = vsplat(W(pb2, j));
#pragma unroll
                for (int i = 0; i < Kk; i++) a = wfma(W(pw2, j * Kk + i), h[i], a);
                o[j] = a; m = vmax(m, a);
            }
            v2f sum = vsplat(0.0f);
#pragma unroll
            for (int j = 0; j < Kk; j++) { o[j] = vexp2(vsplat(LOG2E) * (o[j] - m)); sum = sum + o[j]; }
            v2f r = vrcp(sum);
#pragma unroll
            for (int j = 0; j < Kk; j++) piN[j] = o[j] * r;
        }

        // ---- mu MLP (23 -> 15 -> 15), sigmoid ----
        v2f muN[CKc];
        {
            v2f h[CKc];
#pragma unroll
            for (int j = 0; j < CKc; j++) {
                v2f a = vsplat(W(mb1, j));
#pragma unroll
                for (int i = 0; i < Cc; i++)  a = wfma(W(mw1, j * 23 + i), x[i], a);
#pragma unroll
                for (int i = 0; i < CKc; i++) a = wfma(W(mw1, j * 23 + 3 + i), mu[i], a);
#pragma unroll
                for (int i = 0; i < Kk; i++)  a = wfma(W(mw1, j * 23 + 18 + i), rho[i], a);
                h[j] = vrelu(a);
            }
#pragma unroll
            for (int j = 0; j < CKc; j++) {
                v2f a = vsplat(W(mb2, j));
#pragma unroll
                for (int i = 0; i < CKc; i++) a = wfma(W(mw2, j * CKc + i), h[i], a);
                muN[j] = vsigm(a);
            }
        }

        // ---- sigma MLP (23 -> 5 -> 5): rinvN = exp(-relu(a)) = 1/sigma_new ----
        v2f rinvN[Kk];
        {
            v2f h[Kk];
#pragma unroll
            for (int j = 0; j < Kk; j++) {
                v2f a = vsplat(W(sb1, j));
#pragma unroll
                for (int i = 0; i < Cc; i++)  a = wfma(W(sw1, j * 23 + i), x[i], a);
#pragma unroll
                for (int i = 0; i < CKc; i++) a = wfma(W(sw1, j * 23 + 3 + i), muN[i], a);
#pragma unroll
                for (int i = 0; i < Kk; i++)  a = wfma(W(sw1, j * 23 + 18 + i), rho[i], a);
                h[j] = vrelu(a);
            }
#pragma unroll
            for (int j = 0; j < Kk; j++) {
                v2f a = vsplat(W(sb2, j));
#pragma unroll
                for (int i = 0; i < Kk; i++) a = wfma(W(sw2, j * Kk + i), h[i], a);
                rinvN[j] = vexp2(vsplat(-LOG2E) * vrelu(a));
            }
        }

        // ---- dens2(x; muN, 1/rinvN), gamma MLP (5 -> 5 -> 1), sigmoid ----
        v2f gin[Kk];
#pragma unroll
        for (int k = 0; k < Kk; k++) {
            v2f inv_s2 = rinvN[k] * rinvN[k];
            v2f d0 = x[0] - muN[k * Cc + 0];
            v2f d1 = x[1] - muN[k * Cc + 1];
            v2f d2 = x[2] - muN[k * Cc + 2];
            v2f dist = vfma(d0, d0, vfma(d1, d1, d2 * d2));
            v2f coef = vsplat(C0) * inv_s2 * rinvN[k];
            gin[k] = piN[k] * (coef * vexp2(vsplat(NH_L2E) * dist * inv_s2));
        }
        {
            v2f h[Kk];
#pragma unroll
            for (int j = 0; j < Kk; j++) {
                v2f a = vsplat(W(gb1, j));
#pragma unroll
                for (int i = 0; i < Kk; i++) a = wfma(W(gw1, j * Kk + i), gin[i], a);
                h[j] = vrelu(a);
            }
            v2f go = vsplat(W(gb2, 0));
#pragma unroll
            for (int i = 0; i < Kk; i++) go = wfma(W(gw2, i), h[i], go);
            reinterpret_cast<v2f*>(out + (size_t)(b * Ss + s) * HWc)[rem] = vsigm(go);
        }
#undef W

        // ---- carry state ----
#pragma unroll
        for (int k = 0; k < Kk; k++) { pi[k] = piN[k]; rinv[k] = rinvN[k]; }
#pragma unroll
        for (int j = 0; j < CKc; j++) mu[j] = muN[j];
#pragma unroll
        for (int c = 0; c < Cc; c++) x[c] = xn[c];
    }
}

} // namespace

extern "C" void kernel_launch(void* const* d_in, const int* in_sizes, int n_in,
                              void* d_out, int out_size, void* d_ws, size_t ws_size,
                              hipStream_t stream) {
    const float* frames = (const float*)d_in[0];
    const float* mu0    = (const float*)d_in[2];
    const float* pw1 = (const float*)d_in[3];
    const float* pb1 = (const float*)d_in[4];
    const float* pw2 = (const float*)d_in[5];
    const float* pb2 = (const float*)d_in[6];
    const float* mw1 = (const float*)d_in[7];
    const float* mb1 = (const float*)d_in[8];
    const float* mw2 = (const float*)d_in[9];
    const float* mb2 = (const float*)d_in[10];
    const float* sw1 = (const float*)d_in[11];
    const float* sb1 = (const float*)d_in[12];
    const float* sw2 = (const float*)d_in[13];
    const float* sb2 = (const float*)d_in[14];
    const float* gw1 = (const float*)d_in[15];
    const float* gb1 = (const float*)d_in[16];
    const float* gw2 = (const float*)d_in[17];
    const float* gb2 = (const float*)d_in[18];
    float* out = (float*)d_out;

    const int total2 = Bb * HW2;                     // 294,912 pixel-pairs
    const int grid = (total2 + BLOCK - 1) / BLOCK;   // 2304 blocks of 128

    gmm_seq_kernel<<<grid, BLOCK, 0, stream>>>(
        frames, mu0,
        pw1, pb1, pw2, pb2,
        mw1, mb1, mw2, mb2,
        sw1, sb1, sw2, sb2,
        gw1, gb1, gw2, gb2,
        out);
}

// Round 8
// 275.343 us; speedup vs baseline: 1.2047x; 1.0307x over previous
//
#include <hip/hip_runtime.h>

// GMMNet: B=4,S=8,C=3,H=W=384,K=5. Pointwise per pixel; scan over S carries
// per-pixel state (pi[5], mu[15], rinv[5]=1/sigma) in registers.
//
// Round 8: consolidate all 871 weight floats into ONE contiguous d_ws buffer
// (tiny staging kernel each launch), laid out in consumption order. R7 proved
// the scalar/SMEM weight path (150.7 us, VGPR 52, no LDS); but 16 separate
// base pointers cost 32 SGPRs of addresses and fragment s_load batches,
// exposing lgkmcnt waits (VALUBusy 58%, waves capped at 4.5/SIMD by grid).
// One base + compile-time immediates -> dense s_load_dwordx16 clustering and
// ~30 freed SGPRs of in-flight window. Opaque scalar per-step offset retained
// (blocks loop-invariant weight hoisting into VGPRs - R2's 188-VGPR lesson).

namespace {

constexpr int Kk = 5;
constexpr int Cc = 3;
constexpr int CKc = 15;   // C*K
constexpr int Bb = 4;
constexpr int Ss = 8;
constexpr int HWc = 384 * 384;
constexpr int HW2 = HWc / 2;          // pixel-pairs per image
constexpr int BLOCK = 128;

// Contiguous weight layout (float offsets), consumption order.
constexpr int OPB1 = 0;     // pi_b1   5
constexpr int OPW1 = 5;     // pi_w1   5x10 = 50
constexpr int OPB2 = 55;    // pi_b2   5
constexpr int OPW2 = 60;    // pi_w2   5x5  = 25
constexpr int OMB1 = 85;    // mu_b1   15
constexpr int OMW1 = 100;   // mu_w1   15x23 = 345
constexpr int OMB2 = 445;   // mu_b2   15
constexpr int OMW2 = 460;   // mu_w2   15x15 = 225
constexpr int OSB1 = 685;   // sg_b1   5
constexpr int OSW1 = 690;   // sg_w1   5x23 = 115
constexpr int OSB2 = 805;   // sg_b2   5
constexpr int OSW2 = 810;   // sg_w2   5x5  = 25
constexpr int OGB1 = 835;   // ga_b1   5
constexpr int OGW1 = 840;   // ga_w1   5x5  = 25
constexpr int OGW2 = 865;   // ga_w2   5
constexpr int OGB2 = 870;   // ga_b2   1
constexpr int WTOT = 871;   // 3484 B

typedef float v2f __attribute__((ext_vector_type(2)));

__device__ __forceinline__ float rcpf(float x) { return __builtin_amdgcn_rcpf(x); }
__device__ __forceinline__ float ex2(float x) { return __builtin_amdgcn_exp2f(x); }

__device__ __forceinline__ v2f vsplat(float w) { v2f r = {w, w}; return r; }
__device__ __forceinline__ v2f vfma(v2f a, v2f b, v2f c) { return __builtin_elementwise_fma(a, b, c); }
__device__ __forceinline__ v2f wfma(float w, v2f x, v2f c) { return vfma(vsplat(w), x, c); }
__device__ __forceinline__ v2f vexp2(v2f v) { v2f r; r.x = ex2(v.x); r.y = ex2(v.y); return r; }
__device__ __forceinline__ v2f vrcp(v2f v) { v2f r; r.x = rcpf(v.x); r.y = rcpf(v.y); return r; }
__device__ __forceinline__ v2f vmax(v2f a, v2f b) { return __builtin_elementwise_max(a, b); }
__device__ __forceinline__ v2f vrelu(v2f a) { return vmax(a, vsplat(0.0f)); }
constexpr float LOG2E = 1.4426950408889634f;
__device__ __forceinline__ v2f vsigm(v2f a) { return vrcp(vsplat(1.0f) + vexp2(vsplat(-LOG2E) * a)); }

__global__ __launch_bounds__(256) void stage_ws_kernel(
    const float* __restrict__ pw1, const float* __restrict__ pb1,
    const float* __restrict__ pw2, const float* __restrict__ pb2,
    const float* __restrict__ mw1, const float* __restrict__ mb1,
    const float* __restrict__ mw2, const float* __restrict__ mb2,
    const float* __restrict__ sw1, const float* __restrict__ sb1,
    const float* __restrict__ sw2, const float* __restrict__ sb2,
    const float* __restrict__ gw1, const float* __restrict__ gb1,
    const float* __restrict__ gw2, const float* __restrict__ gb2,
    float* __restrict__ ws)
{
    const int t = threadIdx.x;
    auto cp = [&](const float* src, int off, int n) {
        for (int i = t; i < n; i += 256) ws[off + i] = src[i];
    };
    cp(pb1, OPB1, 5);   cp(pw1, OPW1, 50);
    cp(pb2, OPB2, 5);   cp(pw2, OPW2, 25);
    cp(mb1, OMB1, 15);  cp(mw1, OMW1, 345);
    cp(mb2, OMB2, 15);  cp(mw2, OMW2, 225);
    cp(sb1, OSB1, 5);   cp(sw1, OSW1, 115);
    cp(sb2, OSB2, 5);   cp(sw2, OSW2, 25);
    cp(gb1, OGB1, 5);   cp(gw1, OGW1, 25);
    cp(gw2, OGW2, 5);   cp(gb2, OGB2, 1);
}

__global__ __launch_bounds__(BLOCK) void gmm_seq_kernel(
    const float* __restrict__ frames,
    const float* __restrict__ mu0,
    const float* __restrict__ Wt,     // contiguous weights in d_ws
    float* __restrict__ out)
{
    const int t2 = blockIdx.x * BLOCK + threadIdx.x;   // one thread = 2 adjacent px
    const int b   = t2 / HW2;
    const int rem = t2 - b * HW2;

    const float C0 = 0.06349363593424097f;      // (2*pi)^{-3/2}
    const float NH_L2E = -0.7213475204444817f;  // -0.5 * log2(e)

    // Per-pixel-pair carried state.
    v2f pi[Kk], mu[CKc], rinv[Kk];              // rinv = 1/sigma
#pragma unroll
    for (int k = 0; k < Kk; k++) { pi[k] = vsplat(0.2f); rinv[k] = vsplat(1.0f); }
    {
        const float* mp = mu0 + (size_t)b * CKc * HWc;
#pragma unroll
        for (int j = 0; j < CKc; j++)
            mu[j] = reinterpret_cast<const v2f*>(mp + (size_t)j * HWc)[rem];
    }

    const float* fbase = frames + ((size_t)b * Ss * Cc) * HWc;
    v2f x[Cc];
#pragma unroll
    for (int c = 0; c < Cc; c++)
        x[c] = reinterpret_cast<const v2f*>(fbase + (size_t)c * HWc)[rem];

#pragma unroll 1
    for (int s = 0; s < Ss; s++) {
        // Opaque per-iteration SCALAR offset: value is always 0 but unprovable.
        // Addresses stay wave-uniform (s_load path), loads stay loop-variant
        // (no cross-step hoisting of weight VALUES into registers).
        long woff = 0;
        asm volatile("" : "+s"(woff));
        const float* W = Wt + woff;

        // Prefetch next frame's pixels (clamped index -> branchless).
        const int sn = (s + 1 < Ss) ? s + 1 : s;
        v2f xn[Cc];
        {
            const float* fp = fbase + ((size_t)sn * Cc) * HWc;
#pragma unroll
            for (int c = 0; c < Cc; c++)
                xn[c] = reinterpret_cast<const v2f*>(fp + (size_t)c * HWc)[rem];
        }

        // ---- density(x; mu, 1/rinv) ----
        v2f alpha[Kk], rho[Kk];
#pragma unroll
        for (int k = 0; k < Kk; k++) {
            v2f inv_s2 = rinv[k] * rinv[k];
            v2f d0 = x[0] - mu[k * Cc + 0];
            v2f d1 = x[1] - mu[k * Cc + 1];
            v2f d2 = x[2] - mu[k * Cc + 2];
            v2f dist = vfma(d0, d0, vfma(d1, d1, d2 * d2));
            v2f coef = vsplat(C0) * inv_s2 * rinv[k];      // C0 * rinv^3
            v2f dens = coef * vexp2(vsplat(NH_L2E) * dist * inv_s2);
            alpha[k] = pi[k] * dens;
            rho[k] = alpha[k] * dens;
        }

        // ---- pi MLP (10 -> 5 -> 5) + softmax over K ----
        v2f piN[Kk];
        {
            v2f h[Kk];
#pragma unroll
            for (int j = 0; j < Kk; j++) {
                v2f a = vsplat(W[OPB1 + j]);
#pragma unroll
                for (int i = 0; i < Kk; i++) a = wfma(W[OPW1 + j * 2 * Kk + i], pi[i], a);
#pragma unroll
                for (int i = 0; i < Kk; i++) a = wfma(W[OPW1 + j * 2 * Kk + Kk + i], alpha[i], a);
                h[j] = vrelu(a);
            }
            v2f o[Kk];
            v2f m = vsplat(-1e30f);
#pragma unroll
            for (int j = 0; j < Kk; j++) {
                v2f a = vsplat(W[OPB2 + j]);
#pragma unroll
                for (int i = 0; i < Kk; i++) a = wfma(W[OPW2 + j * Kk + i], h[i], a);
                o[j] = a; m = vmax(m, a);
            }
            v2f sum = vsplat(0.0f);
#pragma unroll
            for (int j = 0; j < Kk; j++) { o[j] = vexp2(vsplat(LOG2E) * (o[j] - m)); sum = sum + o[j]; }
            v2f r = vrcp(sum);
#pragma unroll
            for (int j = 0; j < Kk; j++) piN[j] = o[j] * r;
        }

        // ---- mu MLP (23 -> 15 -> 15), sigmoid ----
        v2f muN[CKc];
        {
            v2f h[CKc];
#pragma unroll
            for (int j = 0; j < CKc; j++) {
                v2f a = vsplat(W[OMB1 + j]);
#pragma unroll
                for (int i = 0; i < Cc; i++)  a = wfma(W[OMW1 + j * 23 + i], x[i], a);
#pragma unroll
                for (int i = 0; i < CKc; i++) a = wfma(W[OMW1 + j * 23 + 3 + i], mu[i], a);
#pragma unroll
                for (int i = 0; i < Kk; i++)  a = wfma(W[OMW1 + j * 23 + 18 + i], rho[i], a);
                h[j] = vrelu(a);
            }
#pragma unroll
            for (int j = 0; j < CKc; j++) {
                v2f a = vsplat(W[OMB2 + j]);
#pragma unroll
                for (int i = 0; i < CKc; i++) a = wfma(W[OMW2 + j * CKc + i], h[i], a);
                muN[j] = vsigm(a);
            }
        }

        // ---- sigma MLP (23 -> 5 -> 5): rinvN = exp(-relu(a)) = 1/sigma_new ----
        v2f rinvN[Kk];
        {
            v2f h[Kk];
#pragma unroll
            for (int j = 0; j < Kk; j++) {
                v2f a = vsplat(W[OSB1 + j]);
#pragma unroll
                for (int i = 0; i < Cc; i++)  a = wfma(W[OSW1 + j * 23 + i], x[i], a);
#pragma unroll
                for (int i = 0; i < CKc; i++) a = wfma(W[OSW1 + j * 23 + 3 + i], muN[i], a);
#pragma unroll
                for (int i = 0; i < Kk; i++)  a = wfma(W[OSW1 + j * 23 + 18 + i], rho[i], a);
                h[j] = vrelu(a);
            }
#pragma unroll
            for (int j = 0; j < Kk; j++) {
                v2f a = vsplat(W[OSB2 + j]);
#pragma unroll
                for (int i = 0; i < Kk; i++) a = wfma(W[OSW2 + j * Kk + i], h[i], a);
                rinvN[j] = vexp2(vsplat(-LOG2E) * vrelu(a));
            }
        }

        // ---- dens2(x; muN, 1/rinvN), gamma MLP (5 -> 5 -> 1), sigmoid ----
        v2f gin[Kk];
#pragma unroll
        for (int k = 0; k < Kk; k++) {
            v2f inv_s2 = rinvN[k] * rinvN[k];
            v2f d0 = x[0] - muN[k * Cc + 0];
            v2f d1 = x[1] - muN[k * Cc + 1];
            v2f d2 = x[2] - muN[k * Cc + 2];
            v2f dist = vfma(d0, d0, vfma(d1, d1, d2 * d2));
            v2f coef = vsplat(C0) * inv_s2 * rinvN[k];
            gin[k] = piN[k] * (coef * vexp2(vsplat(NH_L2E) * dist * inv_s2));
        }
        {
            v2f h[Kk];
#pragma unroll
            for (int j = 0; j < Kk; j++) {
                v2f a = vsplat(W[OGB1 + j]);
#pragma unroll
                for (int i = 0; i < Kk; i++) a = wfma(W[OGW1 + j * Kk + i], gin[i], a);
                h[j] = vrelu(a);
            }
            v2f go = vsplat(W[OGB2]);
#pragma unroll
            for (int i = 0; i < Kk; i++) go = wfma(W[OGW2 + i], h[i], go);
            reinterpret_cast<v2f*>(out + (size_t)(b * Ss + s) * HWc)[rem] = vsigm(go);
        }

        // ---- carry state ----
#pragma unroll
        for (int k = 0; k < Kk; k++) { pi[k] = piN[k]; rinv[k] = rinvN[k]; }
#pragma unroll
        for (int j = 0; j < CKc; j++) mu[j] = muN[j];
#pragma unroll
        for (int c = 0; c < Cc; c++) x[c] = xn[c];
    }
}

} // namespace

extern "C" void kernel_launch(void* const* d_in, const int* in_sizes, int n_in,
                              void* d_out, int out_size, void* d_ws, size_t ws_size,
                              hipStream_t stream) {
    const float* frames = (const float*)d_in[0];
    const float* mu0    = (const float*)d_in[2];
    const float* pw1 = (const float*)d_in[3];
    const float* pb1 = (const float*)d_in[4];
    const float* pw2 = (const float*)d_in[5];
    const float* pb2 = (const float*)d_in[6];
    const float* mw1 = (const float*)d_in[7];
    const float* mb1 = (const float*)d_in[8];
    const float* mw2 = (const float*)d_in[9];
    const float* mb2 = (const float*)d_in[10];
    const float* sw1 = (const float*)d_in[11];
    const float* sb1 = (const float*)d_in[12];
    const float* sw2 = (const float*)d_in[13];
    const float* sb2 = (const float*)d_in[14];
    const float* gw1 = (const float*)d_in[15];
    const float* gb1 = (const float*)d_in[16];
    const float* gw2 = (const float*)d_in[17];
    const float* gb2 = (const float*)d_in[18];
    float* out = (float*)d_out;
    float* ws  = (float*)d_ws;

    // Stage all weights contiguous in d_ws (consumption order).
    stage_ws_kernel<<<1, 256, 0, stream>>>(
        pw1, pb1, pw2, pb2, mw1, mb1, mw2, mb2,
        sw1, sb1, sw2, sb2, gw1, gb1, gw2, gb2, ws);

    const int total2 = Bb * HW2;                     // 294,912 pixel-pairs
    const int grid = (total2 + BLOCK - 1) / BLOCK;   // 2304 blocks of 128

    gmm_seq_kernel<<<grid, BLOCK, 0, stream>>>(frames, mu0, ws, out);
}